// Round 8
// baseline (1193.994 us; speedup 1.0000x reference)
//
#include <hip/hip_runtime.h>
#include <hip/hip_bf16.h>
#include <math.h>
#include <stdint.h>

#define N_TOKENS 16384
#define DIM 4096
#define NEXP 64

typedef const __attribute__((address_space(1))) void gvoid_t;
typedef __attribute__((address_space(3))) void svoid_t;

constexpr int MT = 128;  // tokens per block
constexpr int KC = 32;   // k per staged chunk (8 x 16B slots per row)
constexpr int TM = 8;    // tokens per thread
constexpr int TN = 8;    // experts per thread

// ---------------- K1: logits = x @ W^T (fp32, K-split partials) ----------------
// 256 thr = 16 token-slots (tg) x 8 expert-octets (eg) x 2 k-halves (kh).
// Register tile 8x8 -> 1 LDS read per 16 FMA instrs (LDS pipe ~60% of FMA
// time instead of 100%+). kh-split halves per-thread k work; partial sums go
// to plane 2*by+kh and k2 sums planes (no in-kernel reduction needed).
// x/W both double-buffered via global_load_lds, source-XOR-swizzled (rule 21):
//   x key = row&7  (= tg&7, varies across lanes -> 4-way read, data floor)
//   W key = row>>3 (= eg,   varies across lanes -> 2-way read, free)
__global__ __launch_bounds__(256, 3) void k1_gemm(const float* __restrict__ x,
                                                  const float* __restrict__ W,
                                                  float* __restrict__ P, int KS) {
  __shared__ float xlds[2][MT * KC];    // 2 x 16 KB
  __shared__ float wlds[2][NEXP * KC];  // 2 x 8 KB
  const int tid = threadIdx.x;
  const int lane = tid & 63;
  const int wid = __builtin_amdgcn_readfirstlane(tid >> 6);  // wave 0..3
  const int tg = tid & 15;         // token slot: tokens tg + 16*i
  const int eg = (tid >> 4) & 7;   // expert octet
  const int kh = tid >> 7;         // k-half within chunk
  const int tok0 = blockIdx.x * MT;
  const int k0 = blockIdx.y * KS;

  const int lr = lane >> 3;  // row within one glds instr (8 rows x 128B)
  const int ls = lane & 7;   // 16B slot within row

  float acc[TM][TN] = {};

  // stage x[tok0..+127][kc..+31]: 4 glds/wave, 8 rows (1KB) each
  auto stage_x = [&](int b, int kc) {
#pragma unroll
    for (int q = 0; q < 4; ++q) {
      const int r0 = wid * 32 + q * 8;  // wave-uniform row base
      const int r = r0 + lr;
      const float* src = x + (size_t)(tok0 + r) * DIM + kc + 4 * (ls ^ (r & 7));
      float* dst = &xlds[b][r0 * KC];
      __builtin_amdgcn_global_load_lds((gvoid_t*)src, (svoid_t*)dst, 16, 0, 0);
    }
  };
  // stage W[0..63][kc..+31]: 2 glds/wave, key = row>>3
  auto stage_w = [&](int b, int kc) {
#pragma unroll
    for (int q = 0; q < 2; ++q) {
      const int r0 = wid * 16 + q * 8;  // wave-uniform row base
      const int r = r0 + lr;
      const float* src =
          W + (size_t)r * DIM + kc + 4 * (ls ^ ((r >> 3) & 7));
      float* dst = &wlds[b][r0 * KC];
      __builtin_amdgcn_global_load_lds((gvoid_t*)src, (svoid_t*)dst, 16, 0, 0);
    }
  };

  const int nt = KS / KC;
  stage_x(0, k0);
  stage_w(0, k0);
  __syncthreads();  // vmcnt drained at barrier

  for (int t = 0; t < nt; ++t) {
    const int cur = t & 1;
    if (t + 1 < nt) {  // prefetch overlaps the FMA loop below
      stage_x(cur ^ 1, k0 + (t + 1) * KC);
      stage_w(cur ^ 1, k0 + (t + 1) * KC);
    }

    const float* xb = &xlds[cur][0];
    const float* wbb = &wlds[cur][0];
#pragma unroll
    for (int c = 0; c < 4; ++c) {  // k-quads of this thread's half
      const int s = kh * 4 + c;    // logical 16B slot
      float4 xq[TM];
#pragma unroll
      for (int i = 0; i < TM; ++i) {
        const int row = tg + 16 * i;
        xq[i] = *(const float4*)(xb + row * KC + 4 * (s ^ (row & 7)));
      }
#pragma unroll
      for (int j = 0; j < TN; ++j) {
        const int row = eg * 8 + j;
        const float4 w4 = *(const float4*)(wbb + row * KC + 4 * (s ^ eg));
#pragma unroll
        for (int i = 0; i < TM; ++i) {
          acc[i][j] = fmaf(xq[i].x, w4.x, acc[i][j]);
          acc[i][j] = fmaf(xq[i].y, w4.y, acc[i][j]);
          acc[i][j] = fmaf(xq[i].z, w4.z, acc[i][j]);
          acc[i][j] = fmaf(xq[i].w, w4.w, acc[i][j]);
        }
      }
    }
    __syncthreads();  // drains stage glds; closes buffer reuse
  }

  // write partials to plane 2*by+kh: 8 tokens x 8 experts per thread
  const int plane = blockIdx.y * 2 + kh;
#pragma unroll
  for (int i = 0; i < TM; ++i) {
    const int tok = tok0 + tg + 16 * i;
    float* prow = P + ((size_t)plane * N_TOKENS + tok) * NEXP + eg * TN;
    float4 o0, o1;
    o0.x = acc[i][0]; o0.y = acc[i][1]; o0.z = acc[i][2]; o0.w = acc[i][3];
    o1.x = acc[i][4]; o1.y = acc[i][5]; o1.z = acc[i][6]; o1.w = acc[i][7];
    *(float4*)prow = o0;
    *(float4*)(prow + 4) = o1;
  }
}

// ------------- K2: sum partials, softmax, top-2, chunk histograms -------------
__global__ __launch_bounds__(128) void k2_softmax_top2(const float* __restrict__ P,
                                                       int split,
                                                       float* __restrict__ topw,
                                                       int* __restrict__ sel,
                                                       int* __restrict__ cnt) {
  __shared__ int hist[NEXP];
  const int tid = threadIdx.x;
  const int t = blockIdx.x * 128 + tid;
  if (tid < NEXP) hist[tid] = 0;
  __syncthreads();

  float4 v[16];
  {
    const float* row = P + (size_t)t * NEXP;
#pragma unroll
    for (int c = 0; c < 16; ++c) v[c] = *(const float4*)(row + c * 4);
  }
  for (int s = 1; s < split; ++s) {
    const float* row = P + ((size_t)s * N_TOKENS + t) * NEXP;
#pragma unroll
    for (int c = 0; c < 16; ++c) {
      const float4 u = *(const float4*)(row + c * 4);
      v[c].x += u.x; v[c].y += u.y; v[c].z += u.z; v[c].w += u.w;
    }
  }

  float v0 = -INFINITY, v1 = -INFINITY;
  int i0 = 0, i1 = 0;
#define TOP2_STEP(val, idx)                                   \
  {                                                           \
    const float vv = (val);                                   \
    const int ee = (idx);                                     \
    if (vv > v0) { v1 = v0; i1 = i0; v0 = vv; i0 = ee; }      \
    else if (vv > v1) { v1 = vv; i1 = ee; }                   \
  }
#pragma unroll
  for (int c = 0; c < 16; ++c) {
    TOP2_STEP(v[c].x, c * 4 + 0);
    TOP2_STEP(v[c].y, c * 4 + 1);
    TOP2_STEP(v[c].z, c * 4 + 2);
    TOP2_STEP(v[c].w, c * 4 + 3);
  }
#undef TOP2_STEP

  float denom = 0.f;
#pragma unroll
  for (int c = 0; c < 16; ++c) {
    denom += expf(v[c].x - v0);
    denom += expf(v[c].y - v0);
    denom += expf(v[c].z - v0);
    denom += expf(v[c].w - v0);
  }
  const float w0 = 1.0f / denom;           // expf(0) == 1 exactly
  const float w1 = expf(v1 - v0) / denom;

  topw[t * 2 + 0] = w0;
  topw[t * 2 + 1] = w1;
  sel[t * 2 + 0] = i0;
  sel[t * 2 + 1] = i1;
  atomicAdd(&hist[i0], 1);
  atomicAdd(&hist[i1], 1);
  __syncthreads();
  if (tid < NEXP) cnt[blockIdx.x * NEXP + tid] = hist[tid];
}

// -------- K3: expert totals (counts out), exclusive offsets, chunk bases --------
__global__ void k3_scan(const int* __restrict__ cnt, int* __restrict__ cb,
                        float* __restrict__ counts_out) {
  __shared__ int tot[NEXP];
  const int e = threadIdx.x;  // 64 threads
  int run = 0;
  for (int p = 0; p < 128; ++p) run += cnt[p * NEXP + e];
  tot[e] = run;
  counts_out[e] = (float)run;
  __syncthreads();
  int g = 0;
  for (int q = 0; q < e; ++q) g += tot[q];
  int r = g;
  for (int p = 0; p < 128; ++p) {
    cb[p * NEXP + e] = r;
    r += cnt[p * NEXP + e];
  }
}

// ---------------- K4: stable scatter (counting-sort permutation) ----------------
__global__ __launch_bounds__(256) void k4_scatter(const int* __restrict__ sel,
                                                  const int* __restrict__ cb,
                                                  float* __restrict__ gout) {
  __shared__ int wcnt[4 * NEXP];
  const int tid = threadIdx.x;
  const int s = blockIdx.x * 256 + tid;
  const int e = sel[s];
  const int lane = tid & 63;
  const int wv = tid >> 6;
  wcnt[tid] = 0;
  __syncthreads();

  unsigned long long mask = ~0ull;
#pragma unroll
  for (int b = 0; b < 6; ++b) {
    const unsigned long long bb = __ballot((e >> b) & 1);
    mask &= ((e >> b) & 1) ? bb : ~bb;
  }
  const unsigned long long below = mask & ((1ull << lane) - 1ull);
  const int wr = __popcll(below);
  if (wr == 0) wcnt[wv * NEXP + e] = __popcll(mask);
  __syncthreads();

  int base = cb[blockIdx.x * NEXP + e];
  for (int w2 = 0; w2 < wv; ++w2) base += wcnt[w2 * NEXP + e];
  gout[base + wr] = (float)s;
}

extern "C" void kernel_launch(void* const* d_in, const int* in_sizes, int n_in,
                              void* d_out, int out_size, void* d_ws, size_t ws_size,
                              hipStream_t stream) {
  const float* x = (const float*)d_in[0];
  const float* W = (const float*)d_in[1];
  float* out = (float*)d_out;

  // P has 2*split planes (k-half split inside k1 blocks)
  auto need = [](int s) {
    return (size_t)s * 2 * N_TOKENS * NEXP * 4 + (size_t)N_TOKENS * 2 * 4 +
           2 * (size_t)128 * NEXP * 4;
  };
  int split = 4;
  if (ws_size < need(4)) split = (ws_size >= need(2)) ? 2 : 1;
  const int KS = DIM / split;

  float* P = (float*)d_ws;
  int* sel = (int*)((char*)d_ws + (size_t)split * 2 * N_TOKENS * NEXP * 4);
  int* cnt = sel + N_TOKENS * 2;
  int* cb = cnt + 128 * NEXP;

  hipLaunchKernelGGL(k1_gemm, dim3(N_TOKENS / MT, split), dim3(256), 0, stream,
                     x, W, P, KS);
  hipLaunchKernelGGL(k2_softmax_top2, dim3(N_TOKENS / 128), dim3(128), 0, stream,
                     P, split * 2, out, sel, cnt);
  hipLaunchKernelGGL(k3_scan, dim3(1), dim3(64), 0, stream, cnt, cb,
                     out + 2 * N_TOKENS + 2 * N_TOKENS);
  hipLaunchKernelGGL(k4_scatter, dim3((2 * N_TOKENS) / 256), dim3(256), 0, stream,
                     sel, cb, out + 2 * N_TOKENS);
}

// Round 9
// 156.243 us; speedup vs baseline: 7.6419x; 7.6419x over previous
//
#include <hip/hip_runtime.h>
#include <hip/hip_bf16.h>
#include <math.h>
#include <stdint.h>

#define N_TOKENS 16384
#define DIM 4096
#define NEXP 64

typedef const __attribute__((address_space(1))) void gvoid_t;
typedef __attribute__((address_space(3))) void svoid_t;

constexpr int MT = 128;  // tokens per block
constexpr int KC = 32;   // k per staged chunk (8 x 16B slots per row)
constexpr int TM = 8;    // tokens per thread
constexpr int TN = 4;    // experts per thread

// ---------------- K1: logits = x @ W^T (fp32, K-split partials) ----------------
// 256 thr = 16 token-slots (tg) x 16 expert-quads (ej). Tile 8x4 = 32 accs
// (no spill; LB(256,2) for reg headroom — R8's spill was the whole regression).
// Wave = 16 tg x 4 ej: x-read = 16 distinct rows (4-way broadcast), slot-XOR
// key tg&7 -> 2-way bank alias = free; W-read = 4 distinct rows (16-way
// broadcast) ~3cy. Per 128-FMA quad: ~54 LDS-cy < 64 FMA-cy -> FMA-bound.
// Both operands double-buffered via global_load_lds (source-XOR, linear dest,
// rule-21 involution); stage issued BEFORE compute; 1 barrier/chunk.
__global__ __launch_bounds__(256, 2) void k1_gemm(const float* __restrict__ x,
                                                  const float* __restrict__ W,
                                                  float* __restrict__ P, int KS) {
  __shared__ float xlds[2][MT * KC];    // 2 x 16 KB
  __shared__ float wlds[2][NEXP * KC];  // 2 x 8 KB
  const int tid = threadIdx.x;
  const int lane = tid & 63;
  const int wid = __builtin_amdgcn_readfirstlane(tid >> 6);  // wave 0..3
  const int tg = tid & 15;   // token slot: tokens tg + 16*i
  const int ej = tid >> 4;   // expert quad 0..15
  const int tok0 = blockIdx.x * MT;
  const int k0 = blockIdx.y * KS;

  const int lr = lane >> 3;  // row within one glds instr (8 rows x 128B)
  const int ls = lane & 7;   // 16B slot within row

  float acc[TM][TN] = {};

  // stage x[tok0..+127][kc..+31]: 4 glds/wave, 8 rows (1KB) each
  auto stage_x = [&](int b, int kc) {
#pragma unroll
    for (int q = 0; q < 4; ++q) {
      const int r0 = wid * 32 + q * 8;  // wave-uniform row base
      const int r = r0 + lr;
      const float* src = x + (size_t)(tok0 + r) * DIM + kc + 4 * (ls ^ (r & 7));
      float* dst = &xlds[b][r0 * KC];
      __builtin_amdgcn_global_load_lds((gvoid_t*)src, (svoid_t*)dst, 16, 0, 0);
    }
  };
  // stage W[0..63][kc..+31]: 2 glds/wave, same XOR key (r&7)
  auto stage_w = [&](int b, int kc) {
#pragma unroll
    for (int q = 0; q < 2; ++q) {
      const int r0 = wid * 16 + q * 8;  // wave-uniform row base
      const int r = r0 + lr;
      const float* src = W + (size_t)r * DIM + kc + 4 * (ls ^ (r & 7));
      float* dst = &wlds[b][r0 * KC];
      __builtin_amdgcn_global_load_lds((gvoid_t*)src, (svoid_t*)dst, 16, 0, 0);
    }
  };

  const int nt = KS / KC;
  stage_x(0, k0);
  stage_w(0, k0);
  __syncthreads();  // vmcnt drained at barrier

  const int keyx = tg & 7;
  for (int t = 0; t < nt; ++t) {
    const int cur = t & 1;
    if (t + 1 < nt) {  // prefetch overlaps the FMA loop below
      stage_x(cur ^ 1, k0 + (t + 1) * KC);
      stage_w(cur ^ 1, k0 + (t + 1) * KC);
    }

    const float* xb = &xlds[cur][0];
    const float* wb = &wlds[cur][0];
#pragma unroll
    for (int c = 0; c < 8; ++c) {  // 16B k-quads
      float4 xq[TM];
#pragma unroll
      for (int i = 0; i < TM; ++i)
        xq[i] = *(const float4*)(xb + (tg + 16 * i) * KC + 4 * (c ^ keyx));
#pragma unroll
      for (int j = 0; j < TN; ++j) {
        const int row = ej * TN + j;
        const float4 w4 = *(const float4*)(wb + row * KC + 4 * (c ^ (row & 7)));
#pragma unroll
        for (int i = 0; i < TM; ++i) {
          acc[i][j] = fmaf(xq[i].x, w4.x, acc[i][j]);
          acc[i][j] = fmaf(xq[i].y, w4.y, acc[i][j]);
          acc[i][j] = fmaf(xq[i].z, w4.z, acc[i][j]);
          acc[i][j] = fmaf(xq[i].w, w4.w, acc[i][j]);
        }
      }
    }
    __syncthreads();  // drains stage glds; closes buffer reuse
  }

  // write partials: 8 tokens x 4 experts per thread (1KB/wave stores)
#pragma unroll
  for (int i = 0; i < TM; ++i) {
    const int tok = tok0 + tg + 16 * i;
    float* prow = P + ((size_t)blockIdx.y * N_TOKENS + tok) * NEXP + ej * TN;
    float4 o;
    o.x = acc[i][0]; o.y = acc[i][1]; o.z = acc[i][2]; o.w = acc[i][3];
    *(float4*)prow = o;
  }
}

// ------------- K2: sum partials, softmax, top-2, chunk histograms -------------
__global__ __launch_bounds__(128) void k2_softmax_top2(const float* __restrict__ P,
                                                       int split,
                                                       float* __restrict__ topw,
                                                       int* __restrict__ sel,
                                                       int* __restrict__ cnt) {
  __shared__ int hist[NEXP];
  const int tid = threadIdx.x;
  const int t = blockIdx.x * 128 + tid;
  if (tid < NEXP) hist[tid] = 0;
  __syncthreads();

  float4 v[16];
  {
    const float* row = P + (size_t)t * NEXP;
#pragma unroll
    for (int c = 0; c < 16; ++c) v[c] = *(const float4*)(row + c * 4);
  }
  for (int s = 1; s < split; ++s) {
    const float* row = P + ((size_t)s * N_TOKENS + t) * NEXP;
#pragma unroll
    for (int c = 0; c < 16; ++c) {
      const float4 u = *(const float4*)(row + c * 4);
      v[c].x += u.x; v[c].y += u.y; v[c].z += u.z; v[c].w += u.w;
    }
  }

  float v0 = -INFINITY, v1 = -INFINITY;
  int i0 = 0, i1 = 0;
#define TOP2_STEP(val, idx)                                   \
  {                                                           \
    const float vv = (val);                                   \
    const int ee = (idx);                                     \
    if (vv > v0) { v1 = v0; i1 = i0; v0 = vv; i0 = ee; }      \
    else if (vv > v1) { v1 = vv; i1 = ee; }                   \
  }
#pragma unroll
  for (int c = 0; c < 16; ++c) {
    TOP2_STEP(v[c].x, c * 4 + 0);
    TOP2_STEP(v[c].y, c * 4 + 1);
    TOP2_STEP(v[c].z, c * 4 + 2);
    TOP2_STEP(v[c].w, c * 4 + 3);
  }
#undef TOP2_STEP

  float denom = 0.f;
#pragma unroll
  for (int c = 0; c < 16; ++c) {
    denom += expf(v[c].x - v0);
    denom += expf(v[c].y - v0);
    denom += expf(v[c].z - v0);
    denom += expf(v[c].w - v0);
  }
  const float w0 = 1.0f / denom;           // expf(0) == 1 exactly
  const float w1 = expf(v1 - v0) / denom;

  topw[t * 2 + 0] = w0;
  topw[t * 2 + 1] = w1;
  sel[t * 2 + 0] = i0;
  sel[t * 2 + 1] = i1;
  atomicAdd(&hist[i0], 1);
  atomicAdd(&hist[i1], 1);
  __syncthreads();
  if (tid < NEXP) cnt[blockIdx.x * NEXP + tid] = hist[tid];
}

// -------- K3: expert totals (counts out), exclusive offsets, chunk bases --------
__global__ void k3_scan(const int* __restrict__ cnt, int* __restrict__ cb,
                        float* __restrict__ counts_out) {
  __shared__ int tot[NEXP];
  const int e = threadIdx.x;  // 64 threads
  int run = 0;
  for (int p = 0; p < 128; ++p) run += cnt[p * NEXP + e];
  tot[e] = run;
  counts_out[e] = (float)run;
  __syncthreads();
  int g = 0;
  for (int q = 0; q < e; ++q) g += tot[q];
  int r = g;
  for (int p = 0; p < 128; ++p) {
    cb[p * NEXP + e] = r;
    r += cnt[p * NEXP + e];
  }
}

// ---------------- K4: stable scatter (counting-sort permutation) ----------------
__global__ __launch_bounds__(256) void k4_scatter(const int* __restrict__ sel,
                                                  const int* __restrict__ cb,
                                                  float* __restrict__ gout) {
  __shared__ int wcnt[4 * NEXP];
  const int tid = threadIdx.x;
  const int s = blockIdx.x * 256 + tid;
  const int e = sel[s];
  const int lane = tid & 63;
  const int wv = tid >> 6;
  wcnt[tid] = 0;
  __syncthreads();

  unsigned long long mask = ~0ull;
#pragma unroll
  for (int b = 0; b < 6; ++b) {
    const unsigned long long bb = __ballot((e >> b) & 1);
    mask &= ((e >> b) & 1) ? bb : ~bb;
  }
  const unsigned long long below = mask & ((1ull << lane) - 1ull);
  const int wr = __popcll(below);
  if (wr == 0) wcnt[wv * NEXP + e] = __popcll(mask);
  __syncthreads();

  int base = cb[blockIdx.x * NEXP + e];
  for (int w2 = 0; w2 < wv; ++w2) base += wcnt[w2 * NEXP + e];
  gout[base + wr] = (float)s;
}

extern "C" void kernel_launch(void* const* d_in, const int* in_sizes, int n_in,
                              void* d_out, int out_size, void* d_ws, size_t ws_size,
                              hipStream_t stream) {
  const float* x = (const float*)d_in[0];
  const float* W = (const float*)d_in[1];
  float* out = (float*)d_out;

  auto need = [](int s) {
    return (size_t)s * N_TOKENS * NEXP * 4 + (size_t)N_TOKENS * 2 * 4 +
           2 * (size_t)128 * NEXP * 4;
  };
  int split = 4;  // grid 512 = exactly 2 blocks/CU, no tail
  if (ws_size < need(4)) split = (ws_size >= need(2)) ? 2 : 1;
  const int KS = DIM / split;

  float* P = (float*)d_ws;
  int* sel = (int*)((char*)d_ws + (size_t)split * N_TOKENS * NEXP * 4);
  int* cnt = sel + N_TOKENS * 2;
  int* cb = cnt + 128 * NEXP;

  hipLaunchKernelGGL(k1_gemm, dim3(N_TOKENS / MT, split), dim3(256), 0, stream,
                     x, W, P, KS);
  hipLaunchKernelGGL(k2_softmax_top2, dim3(N_TOKENS / 128), dim3(128), 0, stream,
                     P, split, out, sel, cnt);
  hipLaunchKernelGGL(k3_scan, dim3(1), dim3(64), 0, stream, cnt, cb,
                     out + 2 * N_TOKENS + 2 * N_TOKENS);
  hipLaunchKernelGGL(k4_scatter, dim3((2 * N_TOKENS) / 256), dim3(256), 0, stream,
                     sel, cb, out + 2 * N_TOKENS);
}